// Round 13
// baseline (418.379 us; speedup 1.0000x reference)
//
#include <hip/hip_runtime.h>

#define NEGS   0.2f
#define LN_EPS 1e-5f
#define BSH    7          // 128 nodes per bucket
#define BN     128
#define TILE   4096       // edges per tile block
#define LOG2E  1.44269504f

typedef const float* __restrict__ fp;
typedef _Float16 v2h __attribute__((ext_vector_type(2)));
typedef _Float16 v8h __attribute__((ext_vector_type(8)));
typedef float    v4f __attribute__((ext_vector_type(4)));

__device__ __forceinline__ v2h u2h(unsigned u){ union{unsigned u; v2h h;} c; c.u = u; return c.h; }
__device__ __forceinline__ unsigned h2u(v2h h){ union{v2h h; unsigned u;} c; c.h = h; return c.u; }

// pure-VALU DPP lane-exchange add (hazard nops inserted by backend)
template<int CTRL>
__device__ __forceinline__ float dppadd(float x){
  int y = __builtin_amdgcn_update_dpp(0, __float_as_int(x), CTRL, 0xF, 0xF, true);
  return x + __int_as_float(y);
}
// full sum over each aligned 8-lane group, result replicated in all 8 lanes
__device__ __forceinline__ float hsum8(float s){
  s = dppadd<0xB1>(s);    // xor 1
  s = dppadd<0x4E>(s);    // xor 2
  s = dppadd<0x141>(s);   // row_half_mirror: completes the 8-lane sum
  return s;
}

__device__ __forceinline__ float dot8(v8h a, v8h b, float init){
  union U { v8h v; v2h h[4]; };
  U ua; ua.v = a;
  U ub; ub.v = b;
  float s = init;
  #pragma unroll
  for (int i = 0; i < 4; ++i) s = __builtin_amdgcn_fdot2(ua.h[i], ub.h[i], s, false);
  return s;
}

__device__ __forceinline__ v8h leaky8(v8h t){
  return __builtin_elementwise_max(t, t * (_Float16)NEGS);
}

// edge weight: 8 lanes per node-group, lane holds 8 features (half a head).
__device__ __forceinline__ float edge_w8(v8h v, v8h xr8, v8h att8, float negm2){
  v8h t = leaky8(v + xr8);
  float s = dppadd<0xB1>(dot8(t, att8, negm2));   // 0xB1 = quad_perm xor1
  return __builtin_amdgcn_exp2f(s);
}

// ---------------- setup: blocks 0..5 = weight prep + att pack + pool-acc zeroing
//                         blocks 6..6+ntiles-1 = edge tile histograms (CSR phase 1)
//                         blocks 6+ntiles..    = input transform h = relu(x @ w_in + b_in)
__global__ __launch_bounds__(256) void k_setup(fp x, fp w, fp b, float* __restrict__ h,
                                               unsigned* __restrict__ h16, int N,
                                               fp w_l, fp w_r, fp att,
                                               _Float16* __restrict__ wf, _Float16* __restrict__ att16,
                                               float* __restrict__ gz, int nz,
                                               const int* __restrict__ dstA, int* __restrict__ counts,
                                               int E, int K, int ntiles){
  __shared__ float ws[24*64];
  __shared__ float bs[64];
  __shared__ float xs[4][24];
  __shared__ int hist[512];
  int tid = threadIdx.x;
  if (blockIdx.x < 6){
    int lm = blockIdx.x;              // 0..5 : layer*2 + mat
    if (lm < 3){
      for (int d = tid; d < 64; d += 256)
        att16[lm*64 + d] = (_Float16)(att[lm*64 + d] * LOG2E);
    }
    // zero gsum+embsum (workspace is poisoned each call)
    for (int i = lm*256 + tid; i < nz; i += 6*256) gz[i] = 0.f;
    const float* src = ((lm & 1) ? w_r : w_l) + (lm >> 1)*4096;
    _Float16* dst = wf + lm*4096;
    for (int d = tid; d < 4096; d += 256){
      int jj = d & 7, l = (d >> 3) & 63, kc = (d >> 9) & 1, nt = d >> 10;
      int k = kc*32 + (l >> 4)*8 + jj;
      int n = nt*16 + (l & 15);
      dst[d] = (_Float16)src[k*64 + n];
    }
    return;
  }
  if (blockIdx.x < (unsigned)(6 + ntiles)){
    int t = blockIdx.x - 6;
    for (int i = tid; i < K; i += 256) hist[i] = 0;
    __syncthreads();
    int e0 = t*TILE, e1 = min(e0 + TILE, E);
    for (int e = e0 + tid; e < e1; e += 256)
      atomicAdd(&hist[dstA[e] >> BSH], 1);
    __syncthreads();
    for (int i = tid; i < K; i += 256) counts[i*ntiles + t] = hist[i];
    return;
  }
  int blk = blockIdx.x - 6 - ntiles;
  for (int i = tid; i < 24*64; i += 256) ws[i] = w[i];
  if (tid < 64) bs[tid] = b[tid];
  int r = tid >> 6, c = tid & 63;
  int row = blk*4 + r;
  if (c < 24 && row < N) xs[r][c] = x[row*24 + c];
  __syncthreads();
  float acc = bs[c];
  #pragma unroll
  for (int k = 0; k < 24; ++k) acc = fmaf(xs[r][k], ws[k*64 + c], acc);
  float y = fmaxf(acc, 0.f);
  float y1 = __shfl_down(y, 1);
  if (row < N){
    h[(size_t)row*64 + c] = y;
    if (!(c & 1)){
      v2h p; p.x = (_Float16)y; p.y = (_Float16)y1;
      h16[(size_t)row*32 + (c >> 1)] = h2u(p);
    }
  }
}

// ---------------- fused scan+scatter: each block redundantly computes the two-level prefix
// it needs from raw counts (L2-resident; no cross-block deps), then scatters its tile.
// Block 0 also emits bbase for k_finexfm. Replaces s_scan_tiles + s_scan_buckets + t_scatter.
__global__ __launch_bounds__(512) void t_scatter2(const int* __restrict__ srcA, const int* __restrict__ dstA,
                                                  const int* __restrict__ counts, int* __restrict__ bbase,
                                                  unsigned* __restrict__ packed, int E, int K, int ntiles){
  __shared__ int sS[512];
  __shared__ int gb[512];
  __shared__ int cur[512];
  int t = blockIdx.x, tid = threadIdx.x;
  // per-bucket total S and prefix P over tiles j < t
  int S = 0, P = 0;
  if (tid < K){
    const int* row = counts + (size_t)tid*ntiles;
    for (int j = 0; j < ntiles; ++j){
      int c = row[j];
      S += c;
      P += (j < t) ? c : 0;
    }
  }
  sS[tid] = S;
  __syncthreads();
  for (int off = 1; off < 512; off <<= 1){
    int v = (tid >= off) ? sS[tid - off] : 0;
    __syncthreads();
    sS[tid] += v;
    __syncthreads();
  }
  if (tid < K){
    int B = sS[tid] - S;          // exclusive bucket base
    gb[tid] = B + P;
    cur[tid] = 0;
    if (t == 0) bbase[tid] = B;
  }
  if (t == 0 && tid == 0) bbase[K] = E;
  __syncthreads();
  int e0 = t*TILE, e1 = min(e0 + TILE, E);
  for (int e = e0 + tid; e < e1; e += 512){
    int d = dstA[e], sv = srcA[e];
    int b = d >> BSH;
    int p = atomicAdd(&cur[b], 1);
    packed[gb[b] + p] = ((unsigned)(d & (BN-1)) << 25) | (unsigned)sv;
  }
}

// ---------------- fused: blocks 0..K-1 = fine sort (row_ptr/col); blocks K.. = layer-0 xfm ----------------
__global__ __launch_bounds__(256) void k_finexfm(const unsigned* __restrict__ packed, const int* __restrict__ bbase,
                                                 int* __restrict__ row_ptr, int* __restrict__ col, int N, int K,
                                                 const unsigned* __restrict__ h16, const _Float16* __restrict__ wf,
                                                 fp blg, fp brg,
                                                 unsigned* __restrict__ xl16, unsigned* __restrict__ xr16){
  __shared__ int hist[BN];
  __shared__ int excl[BN];
  int tid = threadIdx.x;
  if (blockIdx.x < (unsigned)K){
    int b = blockIdx.x;
    int node0 = b << BSH;
    int e_base = bbase[b], e_end = bbase[b+1];
    if (tid < BN) hist[tid] = 0;
    __syncthreads();
    for (int e = e_base + tid; e < e_end; e += 256)
      atomicAdd(&hist[packed[e] >> 25], 1);
    __syncthreads();
    int v = (tid < BN) ? hist[tid] : 0;
    if (tid < BN) excl[tid] = v;
    __syncthreads();
    for (int off = 1; off < BN; off <<= 1){
      int t2 = 0;
      if (tid < BN && tid >= off) t2 = excl[tid - off];
      __syncthreads();
      if (tid < BN) excl[tid] += t2;
      __syncthreads();
    }
    int nn = min(BN, N - node0);
    if (tid < nn) row_ptr[node0 + tid] = e_base + excl[tid] - v;
    if (b == K-1 && tid == 0) row_ptr[N] = e_end;
    if (tid < BN) hist[tid] = excl[tid] - v;
    __syncthreads();
    for (int e = e_base + tid; e < e_end; e += 256){
      unsigned u = packed[e];
      int dl = u >> 25;
      int p = atomicAdd(&hist[dl], 1);
      col[e_base + p] = (int)(u & 0x1FFFFFFu);
    }
    return;
  }
  // layer-0 transform (identical to k_xfm)
  int xb = blockIdx.x - K;
  int wave = tid >> 6, lane = tid & 63;
  int quad = lane >> 4, ln = lane & 15;
  int m0 = xb*64 + wave*16;
  if (m0 >= N) return;
  int m = m0 + ln;
  bool mv = m < N;
  v8h a0 = {}, a1 = {};
  if (mv){
    a0 = *(const v8h*)&h16[(size_t)m*32 + quad*4];
    a1 = *(const v8h*)&h16[(size_t)m*32 + 16 + quad*4];
  }
  #pragma unroll
  for (int mat = 0; mat < 2; ++mat){
    const _Float16* wb = wf + mat*4096;
    fp bias = mat ? brg : blg;
    unsigned* dst = mat ? xr16 : xl16;
    #pragma unroll
    for (int nt = 0; nt < 4; ++nt){
      v8h b0 = *(const v8h*)&wb[nt*1024 + lane*8];
      v8h b1 = *(const v8h*)&wb[nt*1024 + 512 + lane*8];
      float bv = bias[nt*16 + ln];
      v4f acc = {bv, bv, bv, bv};
      acc = __builtin_amdgcn_mfma_f32_16x16x32_f16(a0, b0, acc, 0, 0, 0);
      acc = __builtin_amdgcn_mfma_f32_16x16x32_f16(a1, b1, acc, 0, 0, 0);
      #pragma unroll
      for (int r = 0; r < 4; ++r){
        float partner = __shfl_xor(acc[r], 1);
        int node = m0 + quad*4 + r;
        if (!(lane & 1) && node < N){
          v2h p; p.x = (_Float16)acc[r]; p.y = (_Float16)partner;
          dst[(size_t)node*32 + nt*8 + (ln >> 1)] = h2u(p);
        }
      }
    }
  }
}

// ---------------- per-layer transforms via MFMA: xl16/xr16 = f16(h @ w + b) ----------------
__global__ __launch_bounds__(256) void k_xfm(const unsigned* __restrict__ h16,
                                             const _Float16* __restrict__ wf,   // layer base
                                             fp blg, fp brg,
                                             unsigned* __restrict__ xl16, unsigned* __restrict__ xr16, int N){
  int tid = threadIdx.x, wave = tid >> 6, lane = tid & 63;
  int quad = lane >> 4, ln = lane & 15;
  int m0 = blockIdx.x*64 + wave*16;
  if (m0 >= N) return;
  int m = m0 + ln;
  bool mv = m < N;
  v8h a0 = {}, a1 = {};
  if (mv){
    a0 = *(const v8h*)&h16[(size_t)m*32 + quad*4];
    a1 = *(const v8h*)&h16[(size_t)m*32 + 16 + quad*4];
  }
  #pragma unroll
  for (int mat = 0; mat < 2; ++mat){
    const _Float16* wb = wf + mat*4096;
    fp bias = mat ? brg : blg;
    unsigned* dst = mat ? xr16 : xl16;
    #pragma unroll
    for (int nt = 0; nt < 4; ++nt){
      v8h b0 = *(const v8h*)&wb[nt*1024 + lane*8];
      v8h b1 = *(const v8h*)&wb[nt*1024 + 512 + lane*8];
      float bv = bias[nt*16 + ln];
      v4f acc = {bv, bv, bv, bv};
      acc = __builtin_amdgcn_mfma_f32_16x16x32_f16(a0, b0, acc, 0, 0, 0);
      acc = __builtin_amdgcn_mfma_f32_16x16x32_f16(a1, b1, acc, 0, 0, 0);
      #pragma unroll
      for (int r = 0; r < 4; ++r){
        float partner = __shfl_xor(acc[r], 1);
        int node = m0 + quad*4 + r;
        if (!(lane & 1) && node < N){
          v2h p; p.x = (_Float16)acc[r]; p.y = (_Float16)partner;
          dst[(size_t)node*32 + nt*8 + (ln >> 1)] = h2u(p);
        }
      }
    }
  }
}

// ---------------- fused GATv2 aggregation + residual + LayerNorm (+relu) ----------------
// One node per 8-lane group (8 nodes/wave). den/acc lane-local; LN via 3-hop DPP hsum8.
// Unroll-4 edge loop, node-ordered iteration (R7-verified best).
__global__ __launch_bounds__(256) void k_gat(const unsigned* __restrict__ xl16, const unsigned* __restrict__ xr16,
                                             float* __restrict__ h, unsigned* __restrict__ h16,
                                             const int* __restrict__ row_ptr, const int* __restrict__ col,
                                             const _Float16* __restrict__ att16, fp bg, fp lng, fp lnb,
                                             int N, int do_relu){
  int lane = threadIdx.x & 63;
  int g = lane >> 3;          // node slot 0..7 within wave
  int s = lane & 7;           // feature slice: 8s..8s+7 (half of head s>>1)
  int node = (blockIdx.x*4 + (threadIdx.x >> 6))*8 + g;
  bool valid = node < N;
  int nodec = valid ? node : N - 1;

  v8h att8 = *(const v8h*)&att16[s*8];
  v8h xr8  = *(const v8h*)&xr16[(size_t)nodec*32 + s*4];
  v8h xl8  = *(const v8h*)&xl16[(size_t)nodec*32 + s*4];

  // self score m (softmax stabilizer), per head, replicated within lane pairs
  float m = dppadd<0xB1>(dot8(leaky8(xl8 + xr8), att8, 0.f));
  float negm2 = m * -0.5f;

  // self-loop: weight exp2(m-m)=1
  float den = 1.f;
  float acc[8];
  #pragma unroll
  for (int i = 0; i < 8; ++i) acc[i] = (float)xl8[i];

  int e  = row_ptr[nodec];
  int e1 = valid ? row_ptr[nodec + 1] : e;

  for (; e + 4 <= e1; e += 4){
    int j0 = col[e], j1 = col[e+1], j2 = col[e+2], j3 = col[e+3];
    v8h v0 = *(const v8h*)&xl16[(size_t)j0*32 + s*4];
    v8h v1 = *(const v8h*)&xl16[(size_t)j1*32 + s*4];
    v8h v2 = *(const v8h*)&xl16[(size_t)j2*32 + s*4];
    v8h v3 = *(const v8h*)&xl16[(size_t)j3*32 + s*4];
    float w0 = edge_w8(v0, xr8, att8, negm2);
    float w1 = edge_w8(v1, xr8, att8, negm2);
    float w2 = edge_w8(v2, xr8, att8, negm2);
    float w3 = edge_w8(v3, xr8, att8, negm2);
    den += (w0 + w1) + (w2 + w3);
    #pragma unroll
    for (int i = 0; i < 8; ++i){
      acc[i] = fmaf(w0, (float)v0[i], acc[i]);
      acc[i] = fmaf(w1, (float)v1[i], acc[i]);
      acc[i] = fmaf(w2, (float)v2[i], acc[i]);
      acc[i] = fmaf(w3, (float)v3[i], acc[i]);
    }
  }
  for (; e + 2 <= e1; e += 2){
    int j0 = col[e], j1 = col[e+1];
    v8h v0 = *(const v8h*)&xl16[(size_t)j0*32 + s*4];
    v8h v1 = *(const v8h*)&xl16[(size_t)j1*32 + s*4];
    float w0 = edge_w8(v0, xr8, att8, negm2);
    float w1 = edge_w8(v1, xr8, att8, negm2);
    den += w0 + w1;
    #pragma unroll
    for (int i = 0; i < 8; ++i){
      acc[i] = fmaf(w0, (float)v0[i], acc[i]);
      acc[i] = fmaf(w1, (float)v1[i], acc[i]);
    }
  }
  if (e < e1){
    int j0 = col[e];
    v8h v0 = *(const v8h*)&xl16[(size_t)j0*32 + s*4];
    float w0 = edge_w8(v0, xr8, att8, negm2);
    den += w0;
    #pragma unroll
    for (int i = 0; i < 8; ++i) acc[i] = fmaf(w0, (float)v0[i], acc[i]);
  }

  float inv = 1.f / den;

  float4 bgA = *(const float4*)&bg[s*8];
  float4 bgB = *(const float4*)&bg[s*8 + 4];
  float4 hA  = *(const float4*)&h[(size_t)nodec*64 + s*8];
  float4 hB  = *(const float4*)&h[(size_t)nodec*64 + s*8 + 4];
  float res8[8] = {hA.x + bgA.x, hA.y + bgA.y, hA.z + bgA.z, hA.w + bgA.w,
                   hB.x + bgB.x, hB.y + bgB.y, hB.z + bgB.z, hB.w + bgB.w};
  float o8[8];
  float sl = 0.f;
  #pragma unroll
  for (int i = 0; i < 8; ++i){ o8[i] = fmaf(acc[i], inv, res8[i]); sl += o8[i]; }
  sl = hsum8(sl);
  float mean = sl * (1.f/64.f);
  float vsl = 0.f;
  #pragma unroll
  for (int i = 0; i < 8; ++i){ o8[i] -= mean; vsl = fmaf(o8[i], o8[i], vsl); }
  vsl = hsum8(vsl);
  float rs = rsqrtf(vsl * (1.f/64.f) + LN_EPS);

  if (valid){
    float4 lgA = *(const float4*)&lng[s*8], lgB = *(const float4*)&lng[s*8 + 4];
    float4 lbA = *(const float4*)&lnb[s*8], lbB = *(const float4*)&lnb[s*8 + 4];
    float lg8[8] = {lgA.x, lgA.y, lgA.z, lgA.w, lgB.x, lgB.y, lgB.z, lgB.w};
    float lb8[8] = {lbA.x, lbA.y, lbA.z, lbA.w, lbB.x, lbB.y, lbB.z, lbB.w};
    float y[8];
    #pragma unroll
    for (int i = 0; i < 8; ++i){
      y[i] = fmaf(o8[i]*rs, lg8[i], lb8[i]);
      if (do_relu) y[i] = fmaxf(y[i], 0.f);
    }
    float4 yA = {y[0], y[1], y[2], y[3]};
    float4 yB = {y[4], y[5], y[6], y[7]};
    *(float4*)&h[(size_t)node*64 + s*8]     = yA;
    *(float4*)&h[(size_t)node*64 + s*8 + 4] = yB;
    v8h p;
    #pragma unroll
    for (int i = 0; i < 8; ++i) p[i] = (_Float16)y[i];
    *(v8h*)&h16[(size_t)node*32 + s*4] = p;
  }
}

// ---------------- fused gate MLP + pooling accumulate (gate stays in smem; h reused from smem) ----------------
__global__ __launch_bounds__(256) void k_gatemb(const float* __restrict__ h, fp w1, fp b1, fp w2, fp b2,
                                                const int* __restrict__ batch,
                                                float* __restrict__ gsum, float* __restrict__ embsum, int N){
  __shared__ float w1s[2048];
  __shared__ float hrow[16][64];
  __shared__ float sgate[16];
  __shared__ int sbatch[16];
  int tid = threadIdx.x;
  for (int i = tid*4; i < 2048; i += 1024) *(float4*)&w1s[i] = *(const float4*)&w1[i];
  int base = blockIdx.x*16;
  int nrows = min(16, N - base);
  int lim = nrows*64;
  for (int i = tid*4; i < lim; i += 1024)
    *(float4*)&hrow[0][i] = *(const float4*)&h[(size_t)base*64 + i];
  if (tid < nrows) sbatch[tid] = batch[base + tid];
  __syncthreads();
  int wave = tid >> 6, lane = tid & 63;
  int j = lane & 31, half = lane >> 5;
  float b1v = b1[j], w2v = w2[j], b2v = b2[0];
  int k0 = half*32;
  #pragma unroll
  for (int it = 0; it < 4; ++it){
    int r = wave*4 + it;
    if (base + r >= N) break;
    float s = 0.f;
    #pragma unroll 8
    for (int k = k0; k < k0 + 32; ++k) s = fmaf(hrow[r][k], w1s[k*32 + j], s);
    s += __shfl_xor(s, 32);
    float hid = fmaxf(s + b1v, 0.f);
    float contrib = (half == 0) ? hid * w2v : 0.f;
    #pragma unroll
    for (int o = 1; o < 64; o <<= 1) contrib += __shfl_xor(contrib, o);
    if (lane == 0) sgate[r] = contrib + b2v;
  }
  __syncthreads();
  if (wave == 0 && nrows > 0){
    int cur = sbatch[0];
    float acc = 0.f, asum = 0.f;
    for (int i = 0; i < nrows; ++i){
      int g = sbatch[i];
      if (g != cur){
        atomicAdd(&embsum[cur*64 + lane], acc);
        if (lane == 0) atomicAdd(&gsum[cur], asum);
        acc = 0.f; asum = 0.f; cur = g;
      }
      float a = __expf(sgate[i]);
      acc = fmaf(a, hrow[i][lane], acc);
      asum += a;
    }
    atomicAdd(&embsum[cur*64 + lane], acc);
    if (lane == 0) atomicAdd(&gsum[cur], asum);
  }
}

// ---------------- final GEMM ----------------
__global__ __launch_bounds__(64) void k_out(const float* __restrict__ embsum, const float* __restrict__ gsum,
                                            fp w_out, fp b_out, float* __restrict__ out, int G){
  int g = blockIdx.x, lane = threadIdx.x;
  __shared__ float emb[64];
  float gs = gsum[g];
  float inv = (gs > 0.f) ? 1.f/gs : 1.f;
  emb[lane] = embsum[g*64 + lane] * inv;
  __syncthreads();
  float o2 = b_out[lane];
  #pragma unroll 8
  for (int d = 0; d < 64; ++d) o2 = fmaf(emb[d], w_out[d*64 + lane], o2);
  out[g*64 + lane] = fmaxf(o2, 0.f);
}

extern "C" void kernel_launch(void* const* d_in, const int* in_sizes, int n_in,
                              void* d_out, int out_size, void* d_ws, size_t ws_size,
                              hipStream_t stream) {
  const int N = in_sizes[0] / 24;
  const int E = in_sizes[1] / 2;
  const int G = out_size / 64;
  const int K = (N + BN - 1) >> BSH;
  const int ntiles = (E + TILE - 1) / TILE;

  fp x      = (fp)d_in[0];
  const int* edge  = (const int*)d_in[1];
  const int* batch = (const int*)d_in[2];
  fp w_in   = (fp)d_in[3];
  fp b_in   = (fp)d_in[4];
  fp w_l    = (fp)d_in[5];
  fp b_l    = (fp)d_in[6];
  fp w_r    = (fp)d_in[7];
  fp b_r    = (fp)d_in[8];
  fp att    = (fp)d_in[9];
  fp b_gat  = (fp)d_in[10];
  fp ln_g   = (fp)d_in[11];
  fp ln_b   = (fp)d_in[12];
  fp w_g1   = (fp)d_in[13];
  fp b_g1   = (fp)d_in[14];
  fp w_g2   = (fp)d_in[15];
  fp b_g2   = (fp)d_in[16];
  fp w_out  = (fp)d_in[17];
  fp b_out  = (fp)d_in[18];
  float* out = (float*)d_out;

  char* wp = (char*)d_ws;
  auto alloc = [&](size_t bytes) -> char* {
    char* p = wp; wp += (bytes + 255) & ~(size_t)255; return p;
  };
  float*    h       = (float*)    alloc((size_t)N*64*sizeof(float));
  unsigned* h16     = (unsigned*) alloc((size_t)N*32*sizeof(unsigned));
  unsigned* xl16    = (unsigned*) alloc((size_t)N*32*sizeof(unsigned));
  unsigned* xr16    = (unsigned*) alloc((size_t)N*32*sizeof(unsigned));
  int*      col     = (int*)      alloc((size_t)E*sizeof(int));
  unsigned* packed  = (unsigned*) alloc((size_t)E*sizeof(unsigned));
  int*      counts  = (int*)      alloc((size_t)K*ntiles*sizeof(int));
  int*      bbase   = (int*)      alloc((size_t)(K+1)*sizeof(int));
  int*      row_ptr = (int*)      alloc((size_t)(N+1)*sizeof(int));
  float*    gsum    = (float*)    alloc((size_t)(G + G*64)*sizeof(float));
  float*    embsum  = gsum + G;
  _Float16* wf      = (_Float16*) alloc((size_t)3*2*4096*sizeof(_Float16));
  _Float16* att16g  = (_Float16*) alloc((size_t)3*64*sizeof(_Float16));

  const int* srcA = edge;
  const int* dstA = edge + E;

  // fused: weight prep + att pack + pool-acc zeroing + edge histograms + input transform
  k_setup<<<6 + ntiles + (N + 3)/4, 256, 0, stream>>>(x, w_in, b_in, h, h16, N, w_l, w_r, att,
                                                      wf, att16g, gsum, G + G*64,
                                                      dstA, counts, E, K, ntiles);

  // fused scan + scatter (per-block redundant prefix; block 0 emits bbase)
  t_scatter2<<<ntiles, 512, 0, stream>>>(srcA, dstA, counts, bbase, packed, E, K, ntiles);

  // fused: fine sort + layer-0 transform (independent work)
  k_finexfm<<<K + (N + 63)/64, 256, 0, stream>>>(packed, bbase, row_ptr, col, N, K,
                                                 h16, wf, b_l, b_r, xl16, xr16);

  for (int i = 0; i < 3; ++i){
    if (i > 0)
      k_xfm<<<(N + 63)/64, 256, 0, stream>>>(h16, wf + i*8192, b_l + i*64, b_r + i*64,
                                             xl16, xr16, N);
    k_gat<<<(N + 31)/32, 256, 0, stream>>>(xl16, xr16, h, h16, row_ptr, col,
                                           att16g + i*64, b_gat + i*64, ln_g + i*64, ln_b + i*64,
                                           N, i < 2 ? 1 : 0);
  }

  // fused gate MLP + pooling
  k_gatemb<<<(N + 15)/16, 256, 0, stream>>>(h, w_g1, b_g1, w_g2, b_g2, batch, gsum, embsum, N);
  k_out<<<G, 64, 0, stream>>>(embsum, gsum, w_out, b_out, out, G);
}

// Round 14
// 310.101 us; speedup vs baseline: 1.3492x; 1.3492x over previous
//
#include <hip/hip_runtime.h>

#define NEGS   0.2f
#define LN_EPS 1e-5f
#define BSH    7          // 128 nodes per bucket
#define BN     128
#define TILE   4096       // edges per tile block
#define LOG2E  1.44269504f

typedef const float* __restrict__ fp;
typedef _Float16 v2h __attribute__((ext_vector_type(2)));
typedef _Float16 v8h __attribute__((ext_vector_type(8)));
typedef float    v4f __attribute__((ext_vector_type(4)));

__device__ __forceinline__ v2h u2h(unsigned u){ union{unsigned u; v2h h;} c; c.u = u; return c.h; }
__device__ __forceinline__ unsigned h2u(v2h h){ union{v2h h; unsigned u;} c; c.h = h; return c.u; }

// pure-VALU DPP lane-exchange add (hazard nops inserted by backend)
template<int CTRL>
__device__ __forceinline__ float dppadd(float x){
  int y = __builtin_amdgcn_update_dpp(0, __float_as_int(x), CTRL, 0xF, 0xF, true);
  return x + __int_as_float(y);
}
// full sum over each aligned 8-lane group, result replicated in all 8 lanes
__device__ __forceinline__ float hsum8(float s){
  s = dppadd<0xB1>(s);    // xor 1
  s = dppadd<0x4E>(s);    // xor 2
  s = dppadd<0x141>(s);   // row_half_mirror: completes the 8-lane sum
  return s;
}

__device__ __forceinline__ float dot8(v8h a, v8h b, float init){
  union U { v8h v; v2h h[4]; };
  U ua; ua.v = a;
  U ub; ub.v = b;
  float s = init;
  #pragma unroll
  for (int i = 0; i < 4; ++i) s = __builtin_amdgcn_fdot2(ua.h[i], ub.h[i], s, false);
  return s;
}

__device__ __forceinline__ v8h leaky8(v8h t){
  return __builtin_elementwise_max(t, t * (_Float16)NEGS);
}

// edge weight: 8 lanes per node-group, lane holds 8 features (half a head).
__device__ __forceinline__ float edge_w8(v8h v, v8h xr8, v8h att8, float negm2){
  v8h t = leaky8(v + xr8);
  float s = dppadd<0xB1>(dot8(t, att8, negm2));   // 0xB1 = quad_perm xor1
  return __builtin_amdgcn_exp2f(s);
}

// ---------------- setup: blocks 0..5 = weight prep + att pack + pool-acc zeroing
//                         blocks 6..6+ntiles-1 = edge tile histograms (CSR phase 1)
//                         blocks 6+ntiles..    = input transform h = relu(x @ w_in + b_in)
__global__ __launch_bounds__(256) void k_setup(fp x, fp w, fp b, float* __restrict__ h,
                                               unsigned* __restrict__ h16, int N,
                                               fp w_l, fp w_r, fp att,
                                               _Float16* __restrict__ wf, _Float16* __restrict__ att16,
                                               float* __restrict__ gz, int nz,
                                               const int* __restrict__ dstA, int* __restrict__ counts,
                                               int E, int K, int ntiles){
  __shared__ float ws[24*64];
  __shared__ float bs[64];
  __shared__ float xs[4][24];
  __shared__ int hist[512];
  int tid = threadIdx.x;
  if (blockIdx.x < 6){
    int lm = blockIdx.x;              // 0..5 : layer*2 + mat
    if (lm < 3){
      for (int d = tid; d < 64; d += 256)
        att16[lm*64 + d] = (_Float16)(att[lm*64 + d] * LOG2E);
    }
    // zero gsum+embsum (workspace is poisoned each call)
    for (int i = lm*256 + tid; i < nz; i += 6*256) gz[i] = 0.f;
    const float* src = ((lm & 1) ? w_r : w_l) + (lm >> 1)*4096;
    _Float16* dst = wf + lm*4096;
    for (int d = tid; d < 4096; d += 256){
      int jj = d & 7, l = (d >> 3) & 63, kc = (d >> 9) & 1, nt = d >> 10;
      int k = kc*32 + (l >> 4)*8 + jj;
      int n = nt*16 + (l & 15);
      dst[d] = (_Float16)src[k*64 + n];
    }
    return;
  }
  if (blockIdx.x < (unsigned)(6 + ntiles)){
    int t = blockIdx.x - 6;
    for (int i = tid; i < K; i += 256) hist[i] = 0;
    __syncthreads();
    int e0 = t*TILE, e1 = min(e0 + TILE, E);
    for (int e = e0 + tid; e < e1; e += 256)
      atomicAdd(&hist[dstA[e] >> BSH], 1);
    __syncthreads();
    for (int i = tid; i < K; i += 256) counts[i*ntiles + t] = hist[i];
    return;
  }
  int blk = blockIdx.x - 6 - ntiles;
  for (int i = tid; i < 24*64; i += 256) ws[i] = w[i];
  if (tid < 64) bs[tid] = b[tid];
  int r = tid >> 6, c = tid & 63;
  int row = blk*4 + r;
  if (c < 24 && row < N) xs[r][c] = x[row*24 + c];
  __syncthreads();
  float acc = bs[c];
  #pragma unroll
  for (int k = 0; k < 24; ++k) acc = fmaf(xs[r][k], ws[k*64 + c], acc);
  float y = fmaxf(acc, 0.f);
  float y1 = __shfl_down(y, 1);
  if (row < N){
    h[(size_t)row*64 + c] = y;
    if (!(c & 1)){
      v2h p; p.x = (_Float16)y; p.y = (_Float16)y1;
      h16[(size_t)row*32 + (c >> 1)] = h2u(p);
    }
  }
}

// ---------------- CSR scans ----------------
__global__ __launch_bounds__(512) void s_scan_tiles(int* __restrict__ counts, int* __restrict__ btotal,
                                                    int ntiles){
  __shared__ int s[512];
  int b = blockIdx.x, tid = threadIdx.x;
  int v = (tid < ntiles) ? counts[b*ntiles + tid] : 0;
  s[tid] = v;
  __syncthreads();
  for (int off = 1; off < 512; off <<= 1){
    int t = (tid >= off) ? s[tid - off] : 0;
    __syncthreads();
    s[tid] += t;
    __syncthreads();
  }
  if (tid < ntiles) counts[b*ntiles + tid] = s[tid] - v;
  if (tid == 511) btotal[b] = s[511];
}

__global__ __launch_bounds__(512) void s_scan_buckets(const int* __restrict__ btotal,
                                                      int* __restrict__ bbase, int K, int E){
  __shared__ int s[512];
  int tid = threadIdx.x;
  int v = (tid < K) ? btotal[tid] : 0;
  s[tid] = v;
  __syncthreads();
  for (int off = 1; off < 512; off <<= 1){
    int t = (tid >= off) ? s[tid - off] : 0;
    __syncthreads();
    s[tid] += t;
    __syncthreads();
  }
  if (tid < K) bbase[tid] = s[tid] - v;
  if (tid == 0) bbase[K] = E;
}

__global__ __launch_bounds__(256) void t_scatter(const int* __restrict__ srcA, const int* __restrict__ dstA,
                                                 const int* __restrict__ counts, const int* __restrict__ bbase,
                                                 unsigned* __restrict__ packed, int E, int K, int ntiles){
  __shared__ int gb[512];
  __shared__ int cur[512];
  int t = blockIdx.x, tid = threadIdx.x;
  for (int i = tid; i < K; i += 256){
    gb[i] = bbase[i] + counts[i*ntiles + t];
    cur[i] = 0;
  }
  __syncthreads();
  int e0 = t*TILE, e1 = min(e0 + TILE, E);
  for (int e = e0 + tid; e < e1; e += 256){
    int d = dstA[e], sv = srcA[e];
    int b = d >> BSH;
    int p = atomicAdd(&cur[b], 1);
    packed[gb[b] + p] = ((unsigned)(d & (BN-1)) << 25) | (unsigned)sv;
  }
}

// ---------------- fused: blocks 0..K-1 = fine sort (row_ptr/col); blocks K.. = layer-0 xfm ----------------
__global__ __launch_bounds__(256) void k_finexfm(const unsigned* __restrict__ packed, const int* __restrict__ bbase,
                                                 int* __restrict__ row_ptr, int* __restrict__ col, int N, int K,
                                                 const unsigned* __restrict__ h16, const _Float16* __restrict__ wf,
                                                 fp blg, fp brg,
                                                 unsigned* __restrict__ xl16, unsigned* __restrict__ xr16){
  __shared__ int hist[BN];
  __shared__ int excl[BN];
  int tid = threadIdx.x;
  if (blockIdx.x < (unsigned)K){
    int b = blockIdx.x;
    int node0 = b << BSH;
    int e_base = bbase[b], e_end = bbase[b+1];
    if (tid < BN) hist[tid] = 0;
    __syncthreads();
    for (int e = e_base + tid; e < e_end; e += 256)
      atomicAdd(&hist[packed[e] >> 25], 1);
    __syncthreads();
    int v = (tid < BN) ? hist[tid] : 0;
    if (tid < BN) excl[tid] = v;
    __syncthreads();
    for (int off = 1; off < BN; off <<= 1){
      int t2 = 0;
      if (tid < BN && tid >= off) t2 = excl[tid - off];
      __syncthreads();
      if (tid < BN) excl[tid] += t2;
      __syncthreads();
    }
    int nn = min(BN, N - node0);
    if (tid < nn) row_ptr[node0 + tid] = e_base + excl[tid] - v;
    if (b == K-1 && tid == 0) row_ptr[N] = e_end;
    if (tid < BN) hist[tid] = excl[tid] - v;
    __syncthreads();
    for (int e = e_base + tid; e < e_end; e += 256){
      unsigned u = packed[e];
      int dl = u >> 25;
      int p = atomicAdd(&hist[dl], 1);
      col[e_base + p] = (int)(u & 0x1FFFFFFu);
    }
    return;
  }
  // layer-0 transform (identical to k_xfm)
  int xb = blockIdx.x - K;
  int wave = tid >> 6, lane = tid & 63;
  int quad = lane >> 4, ln = lane & 15;
  int m0 = xb*64 + wave*16;
  if (m0 >= N) return;
  int m = m0 + ln;
  bool mv = m < N;
  v8h a0 = {}, a1 = {};
  if (mv){
    a0 = *(const v8h*)&h16[(size_t)m*32 + quad*4];
    a1 = *(const v8h*)&h16[(size_t)m*32 + 16 + quad*4];
  }
  #pragma unroll
  for (int mat = 0; mat < 2; ++mat){
    const _Float16* wb = wf + mat*4096;
    fp bias = mat ? brg : blg;
    unsigned* dst = mat ? xr16 : xl16;
    #pragma unroll
    for (int nt = 0; nt < 4; ++nt){
      v8h b0 = *(const v8h*)&wb[nt*1024 + lane*8];
      v8h b1 = *(const v8h*)&wb[nt*1024 + 512 + lane*8];
      float bv = bias[nt*16 + ln];
      v4f acc = {bv, bv, bv, bv};
      acc = __builtin_amdgcn_mfma_f32_16x16x32_f16(a0, b0, acc, 0, 0, 0);
      acc = __builtin_amdgcn_mfma_f32_16x16x32_f16(a1, b1, acc, 0, 0, 0);
      #pragma unroll
      for (int r = 0; r < 4; ++r){
        float partner = __shfl_xor(acc[r], 1);
        int node = m0 + quad*4 + r;
        if (!(lane & 1) && node < N){
          v2h p; p.x = (_Float16)acc[r]; p.y = (_Float16)partner;
          dst[(size_t)node*32 + nt*8 + (ln >> 1)] = h2u(p);
        }
      }
    }
  }
}

// ---------------- per-layer transforms via MFMA: xl16/xr16 = f16(h @ w + b) ----------------
__global__ __launch_bounds__(256) void k_xfm(const unsigned* __restrict__ h16,
                                             const _Float16* __restrict__ wf,   // layer base
                                             fp blg, fp brg,
                                             unsigned* __restrict__ xl16, unsigned* __restrict__ xr16, int N){
  int tid = threadIdx.x, wave = tid >> 6, lane = tid & 63;
  int quad = lane >> 4, ln = lane & 15;
  int m0 = blockIdx.x*64 + wave*16;
  if (m0 >= N) return;
  int m = m0 + ln;
  bool mv = m < N;
  v8h a0 = {}, a1 = {};
  if (mv){
    a0 = *(const v8h*)&h16[(size_t)m*32 + quad*4];
    a1 = *(const v8h*)&h16[(size_t)m*32 + 16 + quad*4];
  }
  #pragma unroll
  for (int mat = 0; mat < 2; ++mat){
    const _Float16* wb = wf + mat*4096;
    fp bias = mat ? brg : blg;
    unsigned* dst = mat ? xr16 : xl16;
    #pragma unroll
    for (int nt = 0; nt < 4; ++nt){
      v8h b0 = *(const v8h*)&wb[nt*1024 + lane*8];
      v8h b1 = *(const v8h*)&wb[nt*1024 + 512 + lane*8];
      float bv = bias[nt*16 + ln];
      v4f acc = {bv, bv, bv, bv};
      acc = __builtin_amdgcn_mfma_f32_16x16x32_f16(a0, b0, acc, 0, 0, 0);
      acc = __builtin_amdgcn_mfma_f32_16x16x32_f16(a1, b1, acc, 0, 0, 0);
      #pragma unroll
      for (int r = 0; r < 4; ++r){
        float partner = __shfl_xor(acc[r], 1);
        int node = m0 + quad*4 + r;
        if (!(lane & 1) && node < N){
          v2h p; p.x = (_Float16)acc[r]; p.y = (_Float16)partner;
          dst[(size_t)node*32 + nt*8 + (ln >> 1)] = h2u(p);
        }
      }
    }
  }
}

// ---------------- fused GATv2 aggregation + residual + LayerNorm (+relu) ----------------
// One node per 8-lane group (8 nodes/wave). den/acc lane-local; LN via 3-hop DPP hsum8.
// Unroll-4 edge loop, node-ordered iteration (R7-verified best).
__global__ __launch_bounds__(256) void k_gat(const unsigned* __restrict__ xl16, const unsigned* __restrict__ xr16,
                                             float* __restrict__ h, unsigned* __restrict__ h16,
                                             const int* __restrict__ row_ptr, const int* __restrict__ col,
                                             const _Float16* __restrict__ att16, fp bg, fp lng, fp lnb,
                                             int N, int do_relu){
  int lane = threadIdx.x & 63;
  int g = lane >> 3;          // node slot 0..7 within wave
  int s = lane & 7;           // feature slice: 8s..8s+7 (half of head s>>1)
  int node = (blockIdx.x*4 + (threadIdx.x >> 6))*8 + g;
  bool valid = node < N;
  int nodec = valid ? node : N - 1;

  v8h att8 = *(const v8h*)&att16[s*8];
  v8h xr8  = *(const v8h*)&xr16[(size_t)nodec*32 + s*4];
  v8h xl8  = *(const v8h*)&xl16[(size_t)nodec*32 + s*4];

  // self score m (softmax stabilizer), per head, replicated within lane pairs
  float m = dppadd<0xB1>(dot8(leaky8(xl8 + xr8), att8, 0.f));
  float negm2 = m * -0.5f;

  // self-loop: weight exp2(m-m)=1
  float den = 1.f;
  float acc[8];
  #pragma unroll
  for (int i = 0; i < 8; ++i) acc[i] = (float)xl8[i];

  int e  = row_ptr[nodec];
  int e1 = valid ? row_ptr[nodec + 1] : e;

  for (; e + 4 <= e1; e += 4){
    int j0 = col[e], j1 = col[e+1], j2 = col[e+2], j3 = col[e+3];
    v8h v0 = *(const v8h*)&xl16[(size_t)j0*32 + s*4];
    v8h v1 = *(const v8h*)&xl16[(size_t)j1*32 + s*4];
    v8h v2 = *(const v8h*)&xl16[(size_t)j2*32 + s*4];
    v8h v3 = *(const v8h*)&xl16[(size_t)j3*32 + s*4];
    float w0 = edge_w8(v0, xr8, att8, negm2);
    float w1 = edge_w8(v1, xr8, att8, negm2);
    float w2 = edge_w8(v2, xr8, att8, negm2);
    float w3 = edge_w8(v3, xr8, att8, negm2);
    den += (w0 + w1) + (w2 + w3);
    #pragma unroll
    for (int i = 0; i < 8; ++i){
      acc[i] = fmaf(w0, (float)v0[i], acc[i]);
      acc[i] = fmaf(w1, (float)v1[i], acc[i]);
      acc[i] = fmaf(w2, (float)v2[i], acc[i]);
      acc[i] = fmaf(w3, (float)v3[i], acc[i]);
    }
  }
  for (; e + 2 <= e1; e += 2){
    int j0 = col[e], j1 = col[e+1];
    v8h v0 = *(const v8h*)&xl16[(size_t)j0*32 + s*4];
    v8h v1 = *(const v8h*)&xl16[(size_t)j1*32 + s*4];
    float w0 = edge_w8(v0, xr8, att8, negm2);
    float w1 = edge_w8(v1, xr8, att8, negm2);
    den += w0 + w1;
    #pragma unroll
    for (int i = 0; i < 8; ++i){
      acc[i] = fmaf(w0, (float)v0[i], acc[i]);
      acc[i] = fmaf(w1, (float)v1[i], acc[i]);
    }
  }
  if (e < e1){
    int j0 = col[e];
    v8h v0 = *(const v8h*)&xl16[(size_t)j0*32 + s*4];
    float w0 = edge_w8(v0, xr8, att8, negm2);
    den += w0;
    #pragma unroll
    for (int i = 0; i < 8; ++i) acc[i] = fmaf(w0, (float)v0[i], acc[i]);
  }

  float inv = 1.f / den;

  float4 bgA = *(const float4*)&bg[s*8];
  float4 bgB = *(const float4*)&bg[s*8 + 4];
  float4 hA  = *(const float4*)&h[(size_t)nodec*64 + s*8];
  float4 hB  = *(const float4*)&h[(size_t)nodec*64 + s*8 + 4];
  float res8[8] = {hA.x + bgA.x, hA.y + bgA.y, hA.z + bgA.z, hA.w + bgA.w,
                   hB.x + bgB.x, hB.y + bgB.y, hB.z + bgB.z, hB.w + bgB.w};
  float o8[8];
  float sl = 0.f;
  #pragma unroll
  for (int i = 0; i < 8; ++i){ o8[i] = fmaf(acc[i], inv, res8[i]); sl += o8[i]; }
  sl = hsum8(sl);
  float mean = sl * (1.f/64.f);
  float vsl = 0.f;
  #pragma unroll
  for (int i = 0; i < 8; ++i){ o8[i] -= mean; vsl = fmaf(o8[i], o8[i], vsl); }
  vsl = hsum8(vsl);
  float rs = rsqrtf(vsl * (1.f/64.f) + LN_EPS);

  if (valid){
    float4 lgA = *(const float4*)&lng[s*8], lgB = *(const float4*)&lng[s*8 + 4];
    float4 lbA = *(const float4*)&lnb[s*8], lbB = *(const float4*)&lnb[s*8 + 4];
    float lg8[8] = {lgA.x, lgA.y, lgA.z, lgA.w, lgB.x, lgB.y, lgB.z, lgB.w};
    float lb8[8] = {lbA.x, lbA.y, lbA.z, lbA.w, lbB.x, lbB.y, lbB.z, lbB.w};
    float y[8];
    #pragma unroll
    for (int i = 0; i < 8; ++i){
      y[i] = fmaf(o8[i]*rs, lg8[i], lb8[i]);
      if (do_relu) y[i] = fmaxf(y[i], 0.f);
    }
    float4 yA = {y[0], y[1], y[2], y[3]};
    float4 yB = {y[4], y[5], y[6], y[7]};
    *(float4*)&h[(size_t)node*64 + s*8]     = yA;
    *(float4*)&h[(size_t)node*64 + s*8 + 4] = yB;
    v8h p;
    #pragma unroll
    for (int i = 0; i < 8; ++i) p[i] = (_Float16)y[i];
    *(v8h*)&h16[(size_t)node*32 + s*4] = p;
  }
}

// ---------------- fused gate MLP + pooling accumulate (gate stays in smem; h reused from smem) ----------------
__global__ __launch_bounds__(256) void k_gatemb(const float* __restrict__ h, fp w1, fp b1, fp w2, fp b2,
                                                const int* __restrict__ batch,
                                                float* __restrict__ gsum, float* __restrict__ embsum, int N){
  __shared__ float w1s[2048];
  __shared__ float hrow[16][64];
  __shared__ float sgate[16];
  __shared__ int sbatch[16];
  int tid = threadIdx.x;
  for (int i = tid*4; i < 2048; i += 1024) *(float4*)&w1s[i] = *(const float4*)&w1[i];
  int base = blockIdx.x*16;
  int nrows = min(16, N - base);
  int lim = nrows*64;
  for (int i = tid*4; i < lim; i += 1024)
    *(float4*)&hrow[0][i] = *(const float4*)&h[(size_t)base*64 + i];
  if (tid < nrows) sbatch[tid] = batch[base + tid];
  __syncthreads();
  int wave = tid >> 6, lane = tid & 63;
  int j = lane & 31, half = lane >> 5;
  float b1v = b1[j], w2v = w2[j], b2v = b2[0];
  int k0 = half*32;
  #pragma unroll
  for (int it = 0; it < 4; ++it){
    int r = wave*4 + it;
    if (base + r >= N) break;
    float s = 0.f;
    #pragma unroll 8
    for (int k = k0; k < k0 + 32; ++k) s = fmaf(hrow[r][k], w1s[k*32 + j], s);
    s += __shfl_xor(s, 32);
    float hid = fmaxf(s + b1v, 0.f);
    float contrib = (half == 0) ? hid * w2v : 0.f;
    #pragma unroll
    for (int o = 1; o < 64; o <<= 1) contrib += __shfl_xor(contrib, o);
    if (lane == 0) sgate[r] = contrib + b2v;
  }
  __syncthreads();
  if (wave == 0 && nrows > 0){
    int cur = sbatch[0];
    float acc = 0.f, asum = 0.f;
    for (int i = 0; i < nrows; ++i){
      int g = sbatch[i];
      if (g != cur){
        atomicAdd(&embsum[cur*64 + lane], acc);
        if (lane == 0) atomicAdd(&gsum[cur], asum);
        acc = 0.f; asum = 0.f; cur = g;
      }
      float a = __expf(sgate[i]);
      acc = fmaf(a, hrow[i][lane], acc);
      asum += a;
    }
    atomicAdd(&embsum[cur*64 + lane], acc);
    if (lane == 0) atomicAdd(&gsum[cur], asum);
  }
}

// ---------------- final GEMM ----------------
__global__ __launch_bounds__(64) void k_out(const float* __restrict__ embsum, const float* __restrict__ gsum,
                                            fp w_out, fp b_out, float* __restrict__ out, int G){
  int g = blockIdx.x, lane = threadIdx.x;
  __shared__ float emb[64];
  float gs = gsum[g];
  float inv = (gs > 0.f) ? 1.f/gs : 1.f;
  emb[lane] = embsum[g*64 + lane] * inv;
  __syncthreads();
  float o2 = b_out[lane];
  #pragma unroll 8
  for (int d = 0; d < 64; ++d) o2 = fmaf(emb[d], w_out[d*64 + lane], o2);
  out[g*64 + lane] = fmaxf(o2, 0.f);
}

extern "C" void kernel_launch(void* const* d_in, const int* in_sizes, int n_in,
                              void* d_out, int out_size, void* d_ws, size_t ws_size,
                              hipStream_t stream) {
  const int N = in_sizes[0] / 24;
  const int E = in_sizes[1] / 2;
  const int G = out_size / 64;
  const int K = (N + BN - 1) >> BSH;
  const int ntiles = (E + TILE - 1) / TILE;

  fp x      = (fp)d_in[0];
  const int* edge  = (const int*)d_in[1];
  const int* batch = (const int*)d_in[2];
  fp w_in   = (fp)d_in[3];
  fp b_in   = (fp)d_in[4];
  fp w_l    = (fp)d_in[5];
  fp b_l    = (fp)d_in[6];
  fp w_r    = (fp)d_in[7];
  fp b_r    = (fp)d_in[8];
  fp att    = (fp)d_in[9];
  fp b_gat  = (fp)d_in[10];
  fp ln_g   = (fp)d_in[11];
  fp ln_b   = (fp)d_in[12];
  fp w_g1   = (fp)d_in[13];
  fp b_g1   = (fp)d_in[14];
  fp w_g2   = (fp)d_in[15];
  fp b_g2   = (fp)d_in[16];
  fp w_out  = (fp)d_in[17];
  fp b_out  = (fp)d_in[18];
  float* out = (float*)d_out;

  char* wp = (char*)d_ws;
  auto alloc = [&](size_t bytes) -> char* {
    char* p = wp; wp += (bytes + 255) & ~(size_t)255; return p;
  };
  float*    h       = (float*)    alloc((size_t)N*64*sizeof(float));
  unsigned* h16     = (unsigned*) alloc((size_t)N*32*sizeof(unsigned));
  unsigned* xl16    = (unsigned*) alloc((size_t)N*32*sizeof(unsigned));
  unsigned* xr16    = (unsigned*) alloc((size_t)N*32*sizeof(unsigned));
  int*      col     = (int*)      alloc((size_t)E*sizeof(int));
  unsigned* packed  = (unsigned*) alloc((size_t)E*sizeof(unsigned));
  int*      counts  = (int*)      alloc((size_t)K*ntiles*sizeof(int));
  int*      btotal  = (int*)      alloc((size_t)K*sizeof(int));
  int*      bbase   = (int*)      alloc((size_t)(K+1)*sizeof(int));
  int*      row_ptr = (int*)      alloc((size_t)(N+1)*sizeof(int));
  float*    gsum    = (float*)    alloc((size_t)(G + G*64)*sizeof(float));
  float*    embsum  = gsum + G;
  _Float16* wf      = (_Float16*) alloc((size_t)3*2*4096*sizeof(_Float16));
  _Float16* att16g  = (_Float16*) alloc((size_t)3*64*sizeof(_Float16));

  const int* srcA = edge;
  const int* dstA = edge + E;

  // fused: weight prep + att pack + pool-acc zeroing + edge histograms + input transform
  k_setup<<<6 + ntiles + (N + 3)/4, 256, 0, stream>>>(x, w_in, b_in, h, h16, N, w_l, w_r, att,
                                                      wf, att16g, gsum, G + G*64,
                                                      dstA, counts, E, K, ntiles);

  s_scan_tiles<<<K, 512, 0, stream>>>(counts, btotal, ntiles);
  s_scan_buckets<<<1, 512, 0, stream>>>(btotal, bbase, K, E);
  t_scatter<<<ntiles, 256, 0, stream>>>(srcA, dstA, counts, bbase, packed, E, K, ntiles);

  // fused: fine sort + layer-0 transform (independent work)
  k_finexfm<<<K + (N + 63)/64, 256, 0, stream>>>(packed, bbase, row_ptr, col, N, K,
                                                 h16, wf, b_l, b_r, xl16, xr16);

  for (int i = 0; i < 3; ++i){
    if (i > 0)
      k_xfm<<<(N + 63)/64, 256, 0, stream>>>(h16, wf + i*8192, b_l + i*64, b_r + i*64,
                                             xl16, xr16, N);
    k_gat<<<(N + 31)/32, 256, 0, stream>>>(xl16, xr16, h, h16, row_ptr, col,
                                           att16g + i*64, b_gat + i*64, ln_g + i*64, ln_b + i*64,
                                           N, i < 2 ? 1 : 0);
  }

  // fused gate MLP + pooling
  k_gatemb<<<(N + 15)/16, 256, 0, stream>>>(h, w_g1, b_g1, w_g2, b_g2, batch, gsum, embsum, N);
  k_out<<<G, 64, 0, stream>>>(embsum, gsum, w_out, b_out, out, G);
}